// Round 7
// baseline (467.716 us; speedup 1.0000x reference)
//
#include <hip/hip_runtime.h>
#include <hip/hip_bf16.h>

#define NN 40000
#define NE 640000
#define HID 128
#define NCLS 10
#define NGRAPH 16

typedef __attribute__((ext_vector_type(8))) short bf16x8;
typedef __attribute__((ext_vector_type(4))) float f32x4;

__device__ inline float bf2f(unsigned short u) {
    unsigned int x = ((unsigned int)u) << 16;
    return __builtin_bit_cast(float, x);
}
__device__ inline unsigned short f2bf(float f) {
    __hip_bfloat16 h = __float2bfloat16(f);
    return __builtin_bit_cast(unsigned short, h);
}

// ---------------- degree count ----------------
__global__ void k_count_deg(const int* __restrict__ dst, int* __restrict__ deg, int n) {
    int e = blockIdx.x * blockDim.x + threadIdx.x;
    if (e < n) atomicAdd(&deg[__builtin_nontemporal_load(dst + e)], 1);
}

// ---------------- hierarchical scan (+ fused norm) ----------------
__global__ __launch_bounds__(1024) void k_scan1(const int* __restrict__ deg, int* __restrict__ row_start,
                                                int* __restrict__ partial, float* __restrict__ norm) {
    __shared__ int wsum[16];
    int tid = threadIdx.x, lane = tid & 63, wid = tid >> 6;
    int i = blockIdx.x * 1024 + tid;
    int v = (i < NN) ? deg[i] : 0;
    if (i < NN) norm[i] = rsqrtf(fmaxf((float)v, 1.0f));
    int sv = v;
    #pragma unroll
    for (int off = 1; off < 64; off <<= 1) {
        int t = __shfl_up(sv, off);
        if (lane >= off) sv += t;
    }
    if (lane == 63) wsum[wid] = sv;
    __syncthreads();
    if (wid == 0) {
        int ws = (lane < 16) ? wsum[lane] : 0;
        #pragma unroll
        for (int off = 1; off < 16; off <<= 1) {
            int t = __shfl_up(ws, off);
            if (lane >= off) ws += t;
        }
        if (lane < 16) wsum[lane] = ws;
    }
    __syncthreads();
    int excl = (wid > 0 ? wsum[wid - 1] : 0) + (sv - v);
    if (i < NN) row_start[i] = excl;
    if (tid == 0) partial[blockIdx.x] = wsum[15];
}

__global__ void k_scan2(const int* __restrict__ partial, int* __restrict__ offs, int* __restrict__ row_start, int nb) {
    if (threadIdx.x == 0) {
        int acc = 0;
        for (int j = 0; j < nb; ++j) { offs[j] = acc; acc += partial[j]; }
        row_start[NN] = acc;
    }
}

__global__ __launch_bounds__(1024) void k_scan3(int* __restrict__ row_start, const int* __restrict__ offs) {
    int i = blockIdx.x * 1024 + threadIdx.x;
    if (i < NN) row_start[i] += offs[blockIdx.x];
}

// ---------------- CSR bucket fill ----------------
__global__ void k_fill_csr(const int* __restrict__ src, const int* __restrict__ dst,
                           const int* __restrict__ row_start, int* __restrict__ fill,
                           int* __restrict__ csr_src, int n) {
    int e = blockIdx.x * blockDim.x + threadIdx.x;
    if (e < n) {
        int d = __builtin_nontemporal_load(dst + e);
        int sv = __builtin_nontemporal_load(src + e);
        int pos = atomicAdd(&fill[d], 1);
        csr_src[row_start[d] + pos] = sv;
    }
}

// ---------------- converts ----------------
__global__ void k_cvt_h(const float* __restrict__ h, unsigned short* __restrict__ hb) {
    int i = blockIdx.x * 256 + threadIdx.x;
    if (i < NN * HID / 4) {
        float4 v = reinterpret_cast<const float4*>(h)[i];
        ushort4 o;
        o.x = f2bf(v.x); o.y = f2bf(v.y); o.z = f2bf(v.z); o.w = f2bf(v.w);
        reinterpret_cast<ushort4*>(hb)[i] = o;
    }
}

// W[384][128] fp32 -> Wt[128][384] bf16 (both weights in one launch; blockIdx.y selects)
__global__ void k_cvt_wt(const float* __restrict__ W1, const float* __restrict__ W2,
                         unsigned short* __restrict__ W1t, unsigned short* __restrict__ W2t) {
    int t = blockIdx.x * 256 + threadIdx.x;
    const float* W = blockIdx.y ? W2 : W1;
    unsigned short* Wt = blockIdx.y ? W2t : W1t;
    if (t < 384 * HID) {
        int c = t / 384, k = t % 384;
        Wt[t] = f2bf(W[(size_t)k * HID + c]);
    }
}

// ---------------- propagation, sequential feature passes (L2-resident slice) ----------------
// One pass covers 32 cols: per-XCD working set = 40000*32*2B = 2.56 MB < 4 MiB L2.
// Block (64,4) = 4 waves = 4 nodes. Wave: 8 edge-groups x 8 lanes x ushort4 (8B);
// groups stride the edge list by 8; 2-deep unroll -> up to 16 row-gathers in flight.
__global__ __launch_bounds__(256) void k_prop_pass(const unsigned short* __restrict__ x,
                                                   const float* __restrict__ norm,
                                                   const int* __restrict__ row_start,
                                                   const int* __restrict__ csr_src,
                                                   unsigned short* __restrict__ y, int pass) {
    int node = blockIdx.x * 4 + threadIdx.y;
    int lane = threadIdx.x;          // 0..63
    int grp = lane >> 3;             // 0..7
    int sub = lane & 7;              // 0..7
    int colb = pass * 32 + sub * 4;
    const unsigned short* __restrict__ xp = x + colb;
    float a0 = 0.f, a1 = 0.f, a2 = 0.f, a3 = 0.f;
    int s = row_start[node], e = row_start[node + 1];
    int i = s + grp;
    for (; i + 8 < e; i += 16) {
        int c0 = __builtin_nontemporal_load(csr_src + i);
        int c1 = __builtin_nontemporal_load(csr_src + i + 8);
        float s0 = norm[c0], s1 = norm[c1];
        ushort4 v0 = *reinterpret_cast<const ushort4*>(xp + (size_t)c0 * HID);
        ushort4 v1 = *reinterpret_cast<const ushort4*>(xp + (size_t)c1 * HID);
        a0 += s0 * bf2f(v0.x) + s1 * bf2f(v1.x);
        a1 += s0 * bf2f(v0.y) + s1 * bf2f(v1.y);
        a2 += s0 * bf2f(v0.z) + s1 * bf2f(v1.z);
        a3 += s0 * bf2f(v0.w) + s1 * bf2f(v1.w);
    }
    if (i < e) {
        int c0 = __builtin_nontemporal_load(csr_src + i);
        float s0 = norm[c0];
        ushort4 v0 = *reinterpret_cast<const ushort4*>(xp + (size_t)c0 * HID);
        a0 += s0 * bf2f(v0.x);
        a1 += s0 * bf2f(v0.y);
        a2 += s0 * bf2f(v0.z);
        a3 += s0 * bf2f(v0.w);
    }
    // reduce across the 8 groups
    #pragma unroll
    for (int off = 8; off <= 32; off <<= 1) {
        a0 += __shfl_xor(a0, off);
        a1 += __shfl_xor(a1, off);
        a2 += __shfl_xor(a2, off);
        a3 += __shfl_xor(a3, off);
    }
    if (lane < 8) {
        float nd = norm[node];
        ushort4 o;
        o.x = f2bf(nd * a0); o.y = f2bf(nd * a1); o.z = f2bf(nd * a2); o.w = f2bf(nd * a3);
        *reinterpret_cast<ushort4*>(y + (size_t)node * HID + colb) = o;
    }
}

// ---------------- MFMA GEMM ----------------
__global__ __launch_bounds__(128) void k_gemm_mfma(const unsigned short* __restrict__ x0,
                                                   const unsigned short* __restrict__ x1,
                                                   const unsigned short* __restrict__ x2,
                                                   const unsigned short* __restrict__ Wt,
                                                   const float* __restrict__ bias,
                                                   unsigned short* __restrict__ y) {
    int tid = threadIdx.x;
    int wave = tid >> 6;
    int lane = tid & 63;
    int r = lane & 15, kg = lane >> 4;
    int row0 = blockIdx.x * 32 + wave * 16;
    const unsigned short* xs[3] = { x0, x1, x2 };

    f32x4 acc[8];
    #pragma unroll
    for (int cf = 0; cf < 8; ++cf) acc[cf] = (f32x4){0.f, 0.f, 0.f, 0.f};

    #pragma unroll
    for (int kseg = 0; kseg < 3; ++kseg) {
        const unsigned short* __restrict__ xp = xs[kseg] + (size_t)(row0 + r) * HID;
        #pragma unroll
        for (int kb = 0; kb < 4; ++kb) {
            bf16x8 afrag = *reinterpret_cast<const bf16x8*>(xp + kb * 32 + kg * 8);
            #pragma unroll
            for (int cf = 0; cf < 8; ++cf) {
                bf16x8 bfrag = *reinterpret_cast<const bf16x8*>(
                    Wt + (size_t)(cf * 16 + r) * 384 + kseg * 128 + kb * 32 + kg * 8);
                acc[cf] = __builtin_amdgcn_mfma_f32_16x16x32_bf16(afrag, bfrag, acc[cf], 0, 0, 0);
            }
        }
    }
    int orow = row0 + (lane >> 4) * 4;
    int colr = lane & 15;
    #pragma unroll
    for (int cf = 0; cf < 8; ++cf) {
        int col = cf * 16 + colr;
        float bb = bias[col];
        #pragma unroll
        for (int v = 0; v < 4; ++v) {
            float val = fmaxf(acc[cf][v] + bb, 0.f);
            y[(size_t)(orow + v) * HID + col] = f2bf(val);
        }
    }
}

// ---------------- segment max pool: 32-row chunks ----------------
__global__ __launch_bounds__(128) void k_pool_bf(const unsigned short* __restrict__ Z, const int* __restrict__ gid,
                                                 float* __restrict__ pooled, int n) {
    const int CHUNK = 32;
    int d = threadIdx.x;
    int start = blockIdx.x * CHUNK;
    if (start >= n) return;
    int end = min(start + CHUNK, n);
    float m = 0.0f;
    int cg = gid[start];
    int i = start;
    for (; i + 2 <= end; i += 2) {
        int g0 = gid[i], g1 = gid[i + 1];
        float v0 = bf2f(Z[(size_t)i * HID + d]);
        float v1 = bf2f(Z[(size_t)(i + 1) * HID + d]);
        if (g0 != cg) {
            atomicMax((unsigned int*)&pooled[cg * HID + d], __float_as_uint(m));
            m = 0.0f; cg = g0;
        }
        m = fmaxf(m, v0);
        if (g1 != cg) {
            atomicMax((unsigned int*)&pooled[cg * HID + d], __float_as_uint(m));
            m = 0.0f; cg = g1;
        }
        m = fmaxf(m, v1);
    }
    for (; i < end; ++i) {
        int g = gid[i];
        if (g != cg) {
            atomicMax((unsigned int*)&pooled[cg * HID + d], __float_as_uint(m));
            m = 0.0f; cg = g;
        }
        m = fmaxf(m, bf2f(Z[(size_t)i * HID + d]));
    }
    atomicMax((unsigned int*)&pooled[cg * HID + d], __float_as_uint(m));
}

// ---------------- final head ----------------
__global__ void k_head(const float* __restrict__ pooled, const float* __restrict__ Wc,
                       const float* __restrict__ bc, float* __restrict__ out) {
    int t = threadIdx.x;
    if (t < NGRAPH * NCLS) {
        int g = t / NCLS, c = t % NCLS;
        float acc = bc[c];
        for (int k = 0; k < HID; ++k) acc += pooled[g * HID + k] * Wc[k * NCLS + c];
        out[t] = acc;
    }
}

extern "C" void kernel_launch(void* const* d_in, const int* in_sizes, int n_in,
                              void* d_out, int out_size, void* d_ws, size_t ws_size,
                              hipStream_t stream) {
    const float* h   = (const float*)d_in[0];
    const int*   src = (const int*)d_in[1];
    const int*   dst = (const int*)d_in[2];
    const int*   gid = (const int*)d_in[3];
    const float* W1  = (const float*)d_in[4];
    const float* b1  = (const float*)d_in[5];
    const float* W2  = (const float*)d_in[6];
    const float* b2  = (const float*)d_in[7];
    const float* Wc  = (const float*)d_in[8];
    const float* bc  = (const float*)d_in[9];
    float* out = (float*)d_out;

    char* ws = (char*)d_ws;
    size_t off = 0;
    auto alloc = [&](size_t bytes) { void* p = ws + off; off = (off + bytes + 63) & ~(size_t)63; return p; };
    int*   deg       = (int*)alloc((size_t)NN * 4);
    int*   fill      = (int*)alloc((size_t)NN * 4);
    int*   row_start = (int*)alloc((size_t)(NN + 1) * 4);
    int*   csr_src   = (int*)alloc((size_t)NE * 4);
    float* norm      = (float*)alloc((size_t)NN * 4);
    int*   partial   = (int*)alloc(64 * 4);
    int*   offs      = (int*)alloc(64 * 4);
    float* pooled    = (float*)alloc((size_t)NGRAPH * HID * 4);
    unsigned short* W1t = (unsigned short*)alloc((size_t)384 * HID * 2);
    unsigned short* W2t = (unsigned short*)alloc((size_t)384 * HID * 2);
    const size_t FB = (size_t)NN * HID * 2;
    unsigned short* hb  = (unsigned short*)alloc(FB);
    unsigned short* Bb  = (unsigned short*)alloc(FB);
    unsigned short* Cb  = (unsigned short*)alloc(FB);
    unsigned short* Yb  = (unsigned short*)alloc(FB);
    unsigned short* Zb  = (unsigned short*)alloc(FB);

    hipMemsetAsync(deg, 0, (size_t)NN * 4 * 2, stream);
    hipMemsetAsync(pooled, 0, (size_t)NGRAPH * HID * 4, stream);

    const int EB = 256;
    const int SCAN_BLOCKS = (NN + 1023) / 1024;

    // converts first (independent of graph build)
    k_cvt_h<<<(NN * HID / 4 + 255) / 256, 256, 0, stream>>>(h, hb);
    dim3 wgrid((384 * HID + 255) / 256, 2);
    k_cvt_wt<<<wgrid, 256, 0, stream>>>(W1, W2, W1t, W2t);

    // CSR build (+norm fused into scan1)
    k_count_deg<<<(NE + EB - 1) / EB, EB, 0, stream>>>(dst, deg, NE);
    k_scan1<<<SCAN_BLOCKS, 1024, 0, stream>>>(deg, row_start, partial, norm);
    k_scan2<<<1, 64, 0, stream>>>(partial, offs, row_start, SCAN_BLOCKS);
    k_scan3<<<SCAN_BLOCKS, 1024, 0, stream>>>(row_start, offs);
    k_fill_csr<<<(NE + EB - 1) / EB, EB, 0, stream>>>(src, dst, row_start, fill, csr_src, NE);

    dim3 pblk(64, 4);
    int pblocks = NN / 4;     // 10000
    int gblocks = NN / 32;    // 1250

    auto prop = [&](const unsigned short* xin, unsigned short* yout) {
        for (int p = 0; p < 4; ++p)
            k_prop_pass<<<pblocks, pblk, 0, stream>>>(xin, norm, row_start, csr_src, yout, p);
    };

    // layer 1
    prop(hb, Bb);
    prop(Bb, Cb);
    k_gemm_mfma<<<gblocks, 128, 0, stream>>>(hb, Bb, Cb, W1t, b1, Yb);

    // layer 2
    prop(Yb, Bb);
    prop(Bb, Cb);
    k_gemm_mfma<<<gblocks, 128, 0, stream>>>(Yb, Bb, Cb, W2t, b2, Zb);

    // pool + head
    k_pool_bf<<<(NN + 31) / 32, 128, 0, stream>>>(Zb, gid, pooled, NN);
    k_head<<<1, 192, 0, stream>>>(pooled, Wc, bc, out);
}

// Round 8
// 279.498 us; speedup vs baseline: 1.6734x; 1.6734x over previous
//
#include <hip/hip_runtime.h>
#include <hip/hip_bf16.h>

#define NN 40000
#define NE 640000
#define HID 128
#define NCLS 10
#define NGRAPH 16

typedef __attribute__((ext_vector_type(8))) short bf16x8;
typedef __attribute__((ext_vector_type(4))) float f32x4;

__device__ inline float bf2f(unsigned short u) {
    unsigned int x = ((unsigned int)u) << 16;
    return __builtin_bit_cast(float, x);
}
__device__ inline unsigned short f2bf(float f) {
    __hip_bfloat16 h = __float2bfloat16(f);
    return __builtin_bit_cast(unsigned short, h);
}

// ---------------- degree count ----------------
__global__ void k_count_deg(const int* __restrict__ dst, int* __restrict__ deg, int n) {
    int e = blockIdx.x * blockDim.x + threadIdx.x;
    if (e < n) atomicAdd(&deg[__builtin_nontemporal_load(dst + e)], 1);
}

// ---------------- scan stage 1: per-block exclusive scan + block totals (+ fused norm) ----------------
__global__ __launch_bounds__(1024) void k_scan1(const int* __restrict__ deg, int* __restrict__ row_start,
                                                int* __restrict__ partial, float* __restrict__ norm) {
    __shared__ int wsum[16];
    int tid = threadIdx.x, lane = tid & 63, wid = tid >> 6;
    int i = blockIdx.x * 1024 + tid;
    int v = (i < NN) ? deg[i] : 0;
    if (i < NN) norm[i] = rsqrtf(fmaxf((float)v, 1.0f));
    int sv = v;
    #pragma unroll
    for (int off = 1; off < 64; off <<= 1) {
        int t = __shfl_up(sv, off);
        if (lane >= off) sv += t;
    }
    if (lane == 63) wsum[wid] = sv;
    __syncthreads();
    if (wid == 0) {
        int ws = (lane < 16) ? wsum[lane] : 0;
        #pragma unroll
        for (int off = 1; off < 16; off <<= 1) {
            int t = __shfl_up(ws, off);
            if (lane >= off) ws += t;
        }
        if (lane < 16) wsum[lane] = ws;
    }
    __syncthreads();
    int excl = (wid > 0 ? wsum[wid - 1] : 0) + (sv - v);
    if (i < NN) row_start[i] = excl;
    if (tid == 0) partial[blockIdx.x] = wsum[15];
}

// ---------------- scan stage 2 (merged): add carry, emit cursor copy, write total ----------------
// Carry = sum partial[0..bid) computed lane-parallel in wave 0 (nb <= 64).
__global__ __launch_bounds__(1024) void k_scan3(int* __restrict__ row_start, const int* __restrict__ partial,
                                                int* __restrict__ cursor, int nb) {
    __shared__ int sh_carry, sh_all;
    int tid = threadIdx.x;
    if (tid < 64) {
        int v = (tid < nb) ? partial[tid] : 0;
        int lt = (tid < (int)blockIdx.x) ? v : 0;
        #pragma unroll
        for (int off = 32; off; off >>= 1) {
            lt += __shfl_down(lt, off);
            v  += __shfl_down(v, off);
        }
        if (tid == 0) { sh_carry = lt; sh_all = v; }
    }
    __syncthreads();
    int i = blockIdx.x * 1024 + tid;
    if (i < NN) {
        int val = row_start[i] + sh_carry;
        row_start[i] = val;
        cursor[i] = val;
    }
    if (blockIdx.x == 0 && tid == 0) row_start[NN] = sh_all;
}

// ---------------- CSR bucket fill (cursor-based: no row_start gather) ----------------
__global__ void k_fill_csr(const int* __restrict__ src, const int* __restrict__ dst,
                           int* __restrict__ cursor, int* __restrict__ csr_src, int n) {
    int e = blockIdx.x * blockDim.x + threadIdx.x;
    if (e < n) {
        int d = __builtin_nontemporal_load(dst + e);
        int sv = __builtin_nontemporal_load(src + e);
        int pos = atomicAdd(&cursor[d], 1);
        csr_src[pos] = sv;
    }
}

// ---------------- converts ----------------
__global__ void k_cvt_h(const float* __restrict__ h, unsigned short* __restrict__ hb) {
    int i = blockIdx.x * 256 + threadIdx.x;
    if (i < NN * HID / 4) {
        float4 v = reinterpret_cast<const float4*>(h)[i];
        ushort4 o;
        o.x = f2bf(v.x); o.y = f2bf(v.y); o.z = f2bf(v.z); o.w = f2bf(v.w);
        reinterpret_cast<ushort4*>(hb)[i] = o;
    }
}

// W[384][128] fp32 -> Wt[128][384] bf16 (both weights in one launch; blockIdx.y selects)
__global__ void k_cvt_wt(const float* __restrict__ W1, const float* __restrict__ W2,
                         unsigned short* __restrict__ W1t, unsigned short* __restrict__ W2t) {
    int t = blockIdx.x * 256 + threadIdx.x;
    const float* W = blockIdx.y ? W2 : W1;
    unsigned short* Wt = blockIdx.y ? W2t : W1t;
    if (t < 384 * HID) {
        int c = t / 384, k = t % 384;
        Wt[t] = f2bf(W[(size_t)k * HID + c]);
    }
}

// ---------------- propagation: one node per 64-lane wave ----------------
// Block (64,4) = 4 waves = 4 nodes. Wave: half h = lane>>5 handles edges s+h, s+h+2, ...
// unroll 4 with next-batch csr prefetch -> 8 row gathers in flight per wave.
__global__ __launch_bounds__(256) void k_prop_bf(const unsigned short* __restrict__ x, const float* __restrict__ norm,
                                                 const int* __restrict__ row_start, const int* __restrict__ csr_src,
                                                 unsigned short* __restrict__ y) {
    int node = blockIdx.x * 4 + threadIdx.y;
    int lane = threadIdx.x;          // 0..63
    int h = lane >> 5;               // half 0/1
    int sub = lane & 31;             // 0..31
    int colb = sub * 4;
    float a0 = 0.f, a1 = 0.f, a2 = 0.f, a3 = 0.f;
    int s = row_start[node], e = row_start[node + 1];
    int i = s + h;
    if (i + 6 < e) {
        int c0 = csr_src[i], c1 = csr_src[i + 2], c2 = csr_src[i + 4], c3 = csr_src[i + 6];
        int j = i + 8;
        while (true) {
            bool more = (j + 6 < e);
            int n0, n1, n2, n3;
            if (more) {
                n0 = csr_src[j]; n1 = csr_src[j + 2]; n2 = csr_src[j + 4]; n3 = csr_src[j + 6];
            }
            float s0 = norm[c0], s1 = norm[c1], s2 = norm[c2], s3 = norm[c3];
            ushort4 v0 = *reinterpret_cast<const ushort4*>(x + (size_t)c0 * HID + colb);
            ushort4 v1 = *reinterpret_cast<const ushort4*>(x + (size_t)c1 * HID + colb);
            ushort4 v2 = *reinterpret_cast<const ushort4*>(x + (size_t)c2 * HID + colb);
            ushort4 v3 = *reinterpret_cast<const ushort4*>(x + (size_t)c3 * HID + colb);
            a0 += s0 * bf2f(v0.x) + s1 * bf2f(v1.x) + s2 * bf2f(v2.x) + s3 * bf2f(v3.x);
            a1 += s0 * bf2f(v0.y) + s1 * bf2f(v1.y) + s2 * bf2f(v2.y) + s3 * bf2f(v3.y);
            a2 += s0 * bf2f(v0.z) + s1 * bf2f(v1.z) + s2 * bf2f(v2.z) + s3 * bf2f(v3.z);
            a3 += s0 * bf2f(v0.w) + s1 * bf2f(v1.w) + s2 * bf2f(v2.w) + s3 * bf2f(v3.w);
            i = j;
            if (!more) break;
            c0 = n0; c1 = n1; c2 = n2; c3 = n3;
            j += 8;
        }
    }
    for (; i < e; i += 2) {
        int sn = csr_src[i];
        float ns = norm[sn];
        ushort4 v = *reinterpret_cast<const ushort4*>(x + (size_t)sn * HID + colb);
        a0 += ns * bf2f(v.x); a1 += ns * bf2f(v.y); a2 += ns * bf2f(v.z); a3 += ns * bf2f(v.w);
    }
    // combine halves
    a0 += __shfl_xor(a0, 32);
    a1 += __shfl_xor(a1, 32);
    a2 += __shfl_xor(a2, 32);
    a3 += __shfl_xor(a3, 32);
    if (h == 0) {
        float nd = norm[node];
        ushort4 o;
        o.x = f2bf(nd * a0); o.y = f2bf(nd * a1); o.z = f2bf(nd * a2); o.w = f2bf(nd * a3);
        *reinterpret_cast<ushort4*>(y + (size_t)node * HID + colb) = o;
    }
}

// ---------------- MFMA GEMM ----------------
__global__ __launch_bounds__(128) void k_gemm_mfma(const unsigned short* __restrict__ x0,
                                                   const unsigned short* __restrict__ x1,
                                                   const unsigned short* __restrict__ x2,
                                                   const unsigned short* __restrict__ Wt,
                                                   const float* __restrict__ bias,
                                                   unsigned short* __restrict__ y) {
    int tid = threadIdx.x;
    int wave = tid >> 6;
    int lane = tid & 63;
    int r = lane & 15, kg = lane >> 4;
    int row0 = blockIdx.x * 32 + wave * 16;
    const unsigned short* xs[3] = { x0, x1, x2 };

    f32x4 acc[8];
    #pragma unroll
    for (int cf = 0; cf < 8; ++cf) acc[cf] = (f32x4){0.f, 0.f, 0.f, 0.f};

    #pragma unroll
    for (int kseg = 0; kseg < 3; ++kseg) {
        const unsigned short* __restrict__ xp = xs[kseg] + (size_t)(row0 + r) * HID;
        #pragma unroll
        for (int kb = 0; kb < 4; ++kb) {
            bf16x8 afrag = *reinterpret_cast<const bf16x8*>(xp + kb * 32 + kg * 8);
            #pragma unroll
            for (int cf = 0; cf < 8; ++cf) {
                bf16x8 bfrag = *reinterpret_cast<const bf16x8*>(
                    Wt + (size_t)(cf * 16 + r) * 384 + kseg * 128 + kb * 32 + kg * 8);
                acc[cf] = __builtin_amdgcn_mfma_f32_16x16x32_bf16(afrag, bfrag, acc[cf], 0, 0, 0);
            }
        }
    }
    int orow = row0 + (lane >> 4) * 4;
    int colr = lane & 15;
    #pragma unroll
    for (int cf = 0; cf < 8; ++cf) {
        int col = cf * 16 + colr;
        float bb = bias[col];
        #pragma unroll
        for (int v = 0; v < 4; ++v) {
            float val = fmaxf(acc[cf][v] + bb, 0.f);
            y[(size_t)(orow + v) * HID + col] = f2bf(val);
        }
    }
}

// ---------------- segment max pool: 16-row chunks ----------------
__global__ __launch_bounds__(128) void k_pool_bf(const unsigned short* __restrict__ Z, const int* __restrict__ gid,
                                                 float* __restrict__ pooled, int n) {
    const int CHUNK = 16;
    int d = threadIdx.x;
    int start = blockIdx.x * CHUNK;
    if (start >= n) return;
    int end = min(start + CHUNK, n);
    float m = 0.0f;
    int cg = gid[start];
    int i = start;
    for (; i + 2 <= end; i += 2) {
        int g0 = gid[i], g1 = gid[i + 1];
        float v0 = bf2f(Z[(size_t)i * HID + d]);
        float v1 = bf2f(Z[(size_t)(i + 1) * HID + d]);
        if (g0 != cg) {
            atomicMax((unsigned int*)&pooled[cg * HID + d], __float_as_uint(m));
            m = 0.0f; cg = g0;
        }
        m = fmaxf(m, v0);
        if (g1 != cg) {
            atomicMax((unsigned int*)&pooled[cg * HID + d], __float_as_uint(m));
            m = 0.0f; cg = g1;
        }
        m = fmaxf(m, v1);
    }
    for (; i < end; ++i) {
        int g = gid[i];
        if (g != cg) {
            atomicMax((unsigned int*)&pooled[cg * HID + d], __float_as_uint(m));
            m = 0.0f; cg = g;
        }
        m = fmaxf(m, bf2f(Z[(size_t)i * HID + d]));
    }
    atomicMax((unsigned int*)&pooled[cg * HID + d], __float_as_uint(m));
}

// ---------------- final head ----------------
__global__ void k_head(const float* __restrict__ pooled, const float* __restrict__ Wc,
                       const float* __restrict__ bc, float* __restrict__ out) {
    int t = threadIdx.x;
    if (t < NGRAPH * NCLS) {
        int g = t / NCLS, c = t % NCLS;
        float acc = bc[c];
        for (int k = 0; k < HID; ++k) acc += pooled[g * HID + k] * Wc[k * NCLS + c];
        out[t] = acc;
    }
}

extern "C" void kernel_launch(void* const* d_in, const int* in_sizes, int n_in,
                              void* d_out, int out_size, void* d_ws, size_t ws_size,
                              hipStream_t stream) {
    const float* h   = (const float*)d_in[0];
    const int*   src = (const int*)d_in[1];
    const int*   dst = (const int*)d_in[2];
    const int*   gid = (const int*)d_in[3];
    const float* W1  = (const float*)d_in[4];
    const float* b1  = (const float*)d_in[5];
    const float* W2  = (const float*)d_in[6];
    const float* b2  = (const float*)d_in[7];
    const float* Wc  = (const float*)d_in[8];
    const float* bc  = (const float*)d_in[9];
    float* out = (float*)d_out;

    char* ws = (char*)d_ws;
    size_t off = 0;
    auto alloc = [&](size_t bytes) { void* p = ws + off; off = (off + bytes + 63) & ~(size_t)63; return p; };
    int*   deg       = (int*)alloc((size_t)NN * 4);
    int*   cursor    = (int*)alloc((size_t)NN * 4);
    int*   row_start = (int*)alloc((size_t)(NN + 1) * 4);
    int*   csr_src   = (int*)alloc((size_t)NE * 4);
    float* norm      = (float*)alloc((size_t)NN * 4);
    int*   partial   = (int*)alloc(64 * 4);
    float* pooled    = (float*)alloc((size_t)NGRAPH * HID * 4);
    unsigned short* W1t = (unsigned short*)alloc((size_t)384 * HID * 2);
    unsigned short* W2t = (unsigned short*)alloc((size_t)384 * HID * 2);
    const size_t FB = (size_t)NN * HID * 2;
    unsigned short* hb  = (unsigned short*)alloc(FB);
    unsigned short* Bb  = (unsigned short*)alloc(FB);
    unsigned short* Cb  = (unsigned short*)alloc(FB);
    unsigned short* Yb  = (unsigned short*)alloc(FB);
    unsigned short* Zb  = (unsigned short*)alloc(FB);

    hipMemsetAsync(deg, 0, (size_t)NN * 4, stream);
    hipMemsetAsync(pooled, 0, (size_t)NGRAPH * HID * 4, stream);

    const int EB = 256;
    const int SCAN_BLOCKS = (NN + 1023) / 1024;  // 40

    // converts first (independent of graph build)
    k_cvt_h<<<(NN * HID / 4 + 255) / 256, 256, 0, stream>>>(h, hb);
    dim3 wgrid((384 * HID + 255) / 256, 2);
    k_cvt_wt<<<wgrid, 256, 0, stream>>>(W1, W2, W1t, W2t);

    // CSR build (+norm fused into scan1, cursor emitted by scan3)
    k_count_deg<<<(NE + EB - 1) / EB, EB, 0, stream>>>(dst, deg, NE);
    k_scan1<<<SCAN_BLOCKS, 1024, 0, stream>>>(deg, row_start, partial, norm);
    k_scan3<<<SCAN_BLOCKS, 1024, 0, stream>>>(row_start, partial, cursor, SCAN_BLOCKS);
    k_fill_csr<<<(NE + EB - 1) / EB, EB, 0, stream>>>(src, dst, cursor, csr_src, NE);

    dim3 pblk(64, 4);
    int pblocks = NN / 4;     // 10000
    int gblocks = NN / 32;    // 1250

    // layer 1
    k_prop_bf<<<pblocks, pblk, 0, stream>>>(hb, norm, row_start, csr_src, Bb);
    k_prop_bf<<<pblocks, pblk, 0, stream>>>(Bb, norm, row_start, csr_src, Cb);
    k_gemm_mfma<<<gblocks, 128, 0, stream>>>(hb, Bb, Cb, W1t, b1, Yb);

    // layer 2
    k_prop_bf<<<pblocks, pblk, 0, stream>>>(Yb, norm, row_start, csr_src, Bb);
    k_prop_bf<<<pblocks, pblk, 0, stream>>>(Bb, norm, row_start, csr_src, Cb);
    k_gemm_mfma<<<gblocks, 128, 0, stream>>>(Yb, Bb, Cb, W2t, b2, Zb);

    // pool + head
    k_pool_bf<<<(NN + 15) / 16, 128, 0, stream>>>(Zb, gid, pooled, NN);
    k_head<<<1, 192, 0, stream>>>(pooled, Wc, bc, out);
}